// Round 5
// baseline (20.999 us; speedup 1.0000x reference)
//
#include <hip/hip_runtime.h>

#define BEV_H 150
#define BEV_W 150
#define NCAM  6
#define CC    128
#define FH    48
#define FW    88
#define IMG_Hf 480.0f
#define IMG_Wf 800.0f
#define NPTS  24

__device__ __forceinline__ float rdlanef(float x, int l) {
    return __uint_as_float((unsigned)__builtin_amdgcn_readlane((int)__float_as_uint(x), l));
}

struct Trip {
    float4 fTA0, fBA0, fTA1, fBA1, fTB0, fBB0, fTB1, fBB1;
    float  wTA0, wBA0, wTA1, wBA1, wTB0, wBB0, wTB1, wBB1;
};

__device__ __forceinline__ void extract2(unsigned& bal, int base,
                                         int& e0, int& e1, float& s0, float& s1) {
    e0 = base; e1 = base; s0 = 0.f; s1 = 0.f;
    if (bal) {
        e0 = base + __builtin_ctz(bal); bal &= bal - 1; s0 = 1.f;
        if (bal) { e1 = base + __builtin_ctz(bal); bal &= bal - 1; s1 = 1.f; }
        else e1 = e0;
    }
}

__device__ __forceinline__ Trip issue(int eA0, int eA1, int eB0, int eB1,
                                      float sA0, float sA1, float sB0, float sB1,
                                      int iT, int iB,
                                      float wTL, float wTR, float wBL, float wBR,
                                      const float* __restrict__ feat, int loff, bool lowhalf) {
    Trip t;
    const int jTA0 = __builtin_amdgcn_readlane(iT, eA0), jBA0 = __builtin_amdgcn_readlane(iB, eA0);
    const int jTA1 = __builtin_amdgcn_readlane(iT, eA1), jBA1 = __builtin_amdgcn_readlane(iB, eA1);
    const int jTB0 = __builtin_amdgcn_readlane(iT, eB0), jBB0 = __builtin_amdgcn_readlane(iB, eB0);
    const int jTB1 = __builtin_amdgcn_readlane(iT, eB1), jBB1 = __builtin_amdgcn_readlane(iB, eB1);

    t.fTA0 = *(const float4*)(feat + jTA0 + loff);
    t.fBA0 = *(const float4*)(feat + jBA0 + loff);
    t.fTA1 = *(const float4*)(feat + jTA1 + loff);
    t.fBA1 = *(const float4*)(feat + jBA1 + loff);
    t.fTB0 = *(const float4*)(feat + jTB0 + loff);
    t.fBB0 = *(const float4*)(feat + jBB0 + loff);
    t.fTB1 = *(const float4*)(feat + jTB1 + loff);
    t.fBB1 = *(const float4*)(feat + jBB1 + loff);

    t.wTA0 = sA0 * (lowhalf ? rdlanef(wTL, eA0) : rdlanef(wTR, eA0));
    t.wBA0 = sA0 * (lowhalf ? rdlanef(wBL, eA0) : rdlanef(wBR, eA0));
    t.wTA1 = sA1 * (lowhalf ? rdlanef(wTL, eA1) : rdlanef(wTR, eA1));
    t.wBA1 = sA1 * (lowhalf ? rdlanef(wBL, eA1) : rdlanef(wBR, eA1));
    t.wTB0 = sB0 * (lowhalf ? rdlanef(wTL, eB0) : rdlanef(wTR, eB0));
    t.wBB0 = sB0 * (lowhalf ? rdlanef(wBL, eB0) : rdlanef(wBR, eB0));
    t.wTB1 = sB1 * (lowhalf ? rdlanef(wTL, eB1) : rdlanef(wTR, eB1));
    t.wBB1 = sB1 * (lowhalf ? rdlanef(wBL, eB1) : rdlanef(wBR, eB1));
    return t;
}

__device__ __forceinline__ void consume(const Trip& t,
                                        float& aAx, float& aAy, float& aAz, float& aAw,
                                        float& aBx, float& aBy, float& aBz, float& aBw) {
    aAx += t.wTA0 * t.fTA0.x + t.wBA0 * t.fBA0.x + t.wTA1 * t.fTA1.x + t.wBA1 * t.fBA1.x;
    aAy += t.wTA0 * t.fTA0.y + t.wBA0 * t.fBA0.y + t.wTA1 * t.fTA1.y + t.wBA1 * t.fBA1.y;
    aAz += t.wTA0 * t.fTA0.z + t.wBA0 * t.fBA0.z + t.wTA1 * t.fTA1.z + t.wBA1 * t.fBA1.z;
    aAw += t.wTA0 * t.fTA0.w + t.wBA0 * t.fBA0.w + t.wTA1 * t.fTA1.w + t.wBA1 * t.fBA1.w;
    aBx += t.wTB0 * t.fTB0.x + t.wBB0 * t.fBB0.x + t.wTB1 * t.fTB1.x + t.wBB1 * t.fBB1.x;
    aBy += t.wTB0 * t.fTB0.y + t.wBB0 * t.fBB0.y + t.wTB1 * t.fTB1.y + t.wBB1 * t.fBB1.y;
    aBz += t.wTB0 * t.fTB0.z + t.wBB0 * t.fBB0.z + t.wTB1 * t.fTB1.z + t.wBB1 * t.fBB1.z;
    aBw += t.wTB0 * t.fTB0.w + t.wBB0 * t.fBB0.w + t.wTB1 * t.fTB1.w + t.wBB1 * t.fBB1.w;
}

__global__ __launch_bounds__(128) void bev_sample_kernel(
    const float* __restrict__ feat,   // (NCAM, FH, FW, C)
    const float* __restrict__ I_,     // (NCAM, 3, 3)
    const float* __restrict__ E_,     // (NCAM, 4, 4)
    const float* __restrict__ grid,   // (D, 3, BEV_H, BEV_W)
    float* __restrict__ out)          // (Q, C)
{
    const int tid  = threadIdx.x;
    const int lane = tid & 63;
    const int wv   = tid >> 6;
    const int l32  = lane & 31;
    const bool lowhalf = (lane < 32);

    // --- cooperative l2i = I @ E[:3,:] in LDS ---
    __shared__ __align__(16) float s_l2i[NCAM][12];
    if (tid < NCAM * 12) {
        const int n = tid / 12, r = tid % 12;
        const int i = r >> 2, j = r & 3;
        float acc = 0.f;
        #pragma unroll
        for (int k = 0; k < 3; ++k)
            acc += I_[n * 9 + i * 3 + k] * E_[n * 16 + k * 4 + j];
        s_l2i[n][r] = acc;
    }
    __syncthreads();

    // --- 2D-compact XCD regions: 2 rows x 4 cols of patch-space regions ---
    // region r: rows [row0, row0+nrow), cols [col0, col0+wr); launch 8*722 blocks
    const int r   = blockIdx.x & 7;
    const int i   = blockIdx.x >> 3;
    const int row0 = (r < 4) ? 0 : 38;
    const int nrow = (r < 4) ? 38 : 37;
    const int c3   = r & 3;
    const int col0 = c3 * 19;
    const int wr   = (c3 == 3) ? 18 : 19;
    if (i >= nrow * wr) return;
    int ph, pw;
    if (wr == 19) { ph = i / 19; pw = i - ph * 19; }
    else          { ph = i / 18; pw = i - ph * 18; }
    ph += row0; pw += col0;

    const int h  = ph * 2 + wv;
    const int wA = pw * 2;
    const int qA = h * BEV_W + wA;

    // --- projection: lanes 0-23 = cell A, lanes 32-55 = cell B ---
    int   iT = 0, iB = 0;
    float wTL = 0.f, wTR = 0.f, wBL = 0.f, wBR = 0.f;
    bool  m = false;

    const bool actA = (lane < NPTS);
    const bool actB = (lane >= 32) && (lane < 32 + NPTS);
    if (actA || actB) {
        const int n = l32 >> 2;
        const int d = l32 & 3;
        const int wc = wA + (actB ? 1 : 0);

        const float gx = grid[((d * 3 + 0) * BEV_H + h) * BEV_W + wc];
        const float gy = grid[((d * 3 + 1) * BEV_H + h) * BEV_W + wc];
        const float gz = grid[((d * 3 + 2) * BEV_H + h) * BEV_W + wc];
        const float x = gx * 102.4f - 51.2f;
        const float y = gy * 102.4f - 51.2f;
        const float z = gz * 8.0f   - 5.0f;

        const float4 M0 = *(const float4*)&s_l2i[n][0];
        const float4 M1 = *(const float4*)&s_l2i[n][4];
        const float4 M2 = *(const float4*)&s_l2i[n][8];
        const float p0 = M0.x * x + M0.y * y + M0.z * z + M0.w;
        const float p1 = M1.x * x + M1.y * y + M1.z * z + M1.w;
        const float p2 = M2.x * x + M2.y * y + M2.z * z + M2.w;

        const float eps = 1e-5f;
        const float zc = fmaxf(p2, eps);
        const float u = (p0 / zc) * (1.0f / IMG_Wf);
        const float v = (p1 / zc) * (1.0f / IMG_Hf);
        m = (p2 > eps) && (u > 0.f) && (u < 1.f) && (v > 0.f) && (v < 1.f);

        const float px = u * (float)FW - 0.5f;
        const float py = v * (float)FH - 0.5f;
        const float fx0 = floorf(px), fy0 = floorf(py);
        const int x0 = (int)fx0, y0 = (int)fy0;
        const int x1 = x0 + 1,   y1 = y0 + 1;
        const float wx1 = px - fx0, wy1 = py - fy0;
        const float wx0 = 1.f - wx1, wy0 = 1.f - wy1;

        const bool vx0 = (x0 >= 0) && (x0 < FW);
        const bool vx1 = (x1 >= 0) && (x1 < FW);
        const bool vy0 = (y0 >= 0) && (y0 < FH);
        const bool vy1 = (y1 >= 0) && (y1 < FH);
        const int cx0 = min(max(x0, 0), FW - 1), cx1 = min(max(x1, 0), FW - 1);
        const int cy0 = min(max(y0, 0), FH - 1), cy1 = min(max(y1, 0), FH - 1);

        const float w0v = wx0 * wy0 * ((vx0 && vy0) ? 1.f : 0.f);
        const float w1v = wx1 * wy0 * ((vx1 && vy0) ? 1.f : 0.f);
        const float w2v = wx0 * wy1 * ((vx0 && vy1) ? 1.f : 0.f);
        const float w3v = wx1 * wy1 * ((vx1 && vy1) ? 1.f : 0.f);

        const int bx = min(max(x0, 0), FW - 2);
        wTL = ((cx0 == bx)     ? w0v : 0.f) + ((cx1 == bx)     ? w1v : 0.f);
        wTR = ((cx0 == bx + 1) ? w0v : 0.f) + ((cx1 == bx + 1) ? w1v : 0.f);
        wBL = ((cx0 == bx)     ? w2v : 0.f) + ((cx1 == bx)     ? w3v : 0.f);
        wBR = ((cx0 == bx + 1) ? w2v : 0.f) + ((cx1 == bx + 1) ? w3v : 0.f);

        const int base = n * FH * FW;
        iT = (base + cy0 * FW + bx) * CC;
        iB = (base + cy1 * FW + bx) * CC;
    }

    const unsigned long long bal = __ballot(m);
    unsigned balA = (unsigned)(bal & 0xFFFFFFull);
    unsigned balB = (unsigned)((bal >> 32) & 0xFFFFFFull);
    const float cntA = fmaxf((float)__popc(balA), 1.f);
    const float cntB = fmaxf((float)__popc(balB), 1.f);

    float aAx = 0.f, aAy = 0.f, aAz = 0.f, aAw = 0.f;
    float aBx = 0.f, aBy = 0.f, aBz = 0.f, aBw = 0.f;
    const int loff = 4 * lane;
    const bool any = (balA | balB) != 0u;

    // --- 2-deep software-pipelined gather: issue trip t+1 before consuming t ---
    int eA0, eA1, eB0, eB1; float sA0, sA1, sB0, sB1;
    extract2(balA, 0,  eA0, eA1, sA0, sA1);
    extract2(balB, 32, eB0, eB1, sB0, sB1);
    Trip cur = issue(eA0, eA1, eB0, eB1, sA0, sA1, sB0, sB1,
                     iT, iB, wTL, wTR, wBL, wBR, feat, loff, lowhalf);

    while (balA | balB) {
        extract2(balA, 0,  eA0, eA1, sA0, sA1);
        extract2(balB, 32, eB0, eB1, sB0, sB1);
        Trip nxt = issue(eA0, eA1, eB0, eB1, sA0, sA1, sB0, sB1,
                         iT, iB, wTL, wTR, wBL, wBR, feat, loff, lowhalf);
        consume(cur, aAx, aAy, aAz, aAw, aBx, aBy, aBz, aBw);
        cur = nxt;
    }
    if (any) consume(cur, aAx, aAy, aAz, aAw, aBx, aBy, aBz, aBw);

    // combine column halves (lane l <-> l+32)
    aAx += __shfl_xor(aAx, 32);  aAy += __shfl_xor(aAy, 32);
    aAz += __shfl_xor(aAz, 32);  aAw += __shfl_xor(aAw, 32);
    aBx += __shfl_xor(aBx, 32);  aBy += __shfl_xor(aBy, 32);
    aBz += __shfl_xor(aBz, 32);  aBw += __shfl_xor(aBw, 32);

    const float inv = lowhalf ? (1.f / cntA) : (1.f / cntB);
    const int   q   = lowhalf ? qA : (qA + 1);
    float4 o;
    o.x = (lowhalf ? aAx : aBx) * inv;
    o.y = (lowhalf ? aAy : aBy) * inv;
    o.z = (lowhalf ? aAz : aBz) * inv;
    o.w = (lowhalf ? aAw : aBw) * inv;
    *(float4*)(out + q * CC + 4 * l32) = o;
}

extern "C" void kernel_launch(void* const* d_in, const int* in_sizes, int n_in,
                              void* d_out, int out_size, void* d_ws, size_t ws_size,
                              hipStream_t stream) {
    const float* feat = (const float*)d_in[0];
    const float* I_   = (const float*)d_in[1];
    const float* E_   = (const float*)d_in[2];
    const float* grid = (const float*)d_in[3];
    float* out        = (float*)d_out;

    // 8 regions x 722 slots (38x19 max region), partial blocks early-exit
    bev_sample_kernel<<<8 * 722, 128, 0, stream>>>(feat, I_, E_, grid, out);
}